// Round 1
// baseline (319.315 us; speedup 1.0000x reference)
//
#include <hip/hip_runtime.h>
#include <cstdint>
#include <cstddef>

#define TT 8192
#define DIN 1024
#define DHID 2048
#define DOUT 1024
#define NCHUNK 128
#define CLEN 64  // TT / NCHUNK

typedef __bf16 bf16x8 __attribute__((ext_vector_type(8)));
typedef float f32x4 __attribute__((ext_vector_type(4)));
using u32_as1 = __attribute__((address_space(1))) const unsigned int;
using u32_as3 = __attribute__((address_space(3))) unsigned int;

__device__ __forceinline__ unsigned short bf16r(float x) {
  unsigned int u = __float_as_uint(x);
  u += 0x7fffu + ((u >> 16) & 1u);
  return (unsigned short)(u >> 16);
}

__global__ void cast_f32_bf16(const float* __restrict__ in, unsigned short* __restrict__ out, int n4) {
  int i = blockIdx.x * 256 + threadIdx.x;
  if (i >= n4) return;
  const float4 v = reinterpret_cast<const float4*>(in)[i];
  ushort4 o;
  o.x = bf16r(v.x);
  o.y = bf16r(v.y);
  o.z = bf16r(v.z);
  o.w = bf16r(v.w);
  reinterpret_cast<ushort4*>(out)[i] = o;
}

__global__ void dec_kernel(const float* __restrict__ pre_a, float* __restrict__ dec) {
  const int d = blockIdx.x * 256 + threadIdx.x;
  if (d < DHID) dec[d] = -8.0f * log1pf(expf(pre_a[d]));
}

// ---------------- GEMM: out[t][n] = sum_k A[t][k] * B[n][k] + bias[n] ----------------
// A: [M][KDIM] bf16 row-major, B: [NDIM][KDIM] bf16 row-major (i.e. B^T input)
// 128x128 tile, BK=32, 4 waves, each wave 64x64 (4x4 frags of 16x16x32 bf16 MFMA)
struct GemmPtrs {
  const unsigned short* B0;
  const unsigned short* B1;
  const unsigned short* B2;
  const float* bias0;
  const float* bias1;
  const float* bias2;
  float* out0;
  float* out1;
  float* out2;
};

template <int KDIM, int NDIM>
__global__ __launch_bounds__(256) void gemm_bt(const unsigned short* __restrict__ A, GemmPtrs gp) {
  __shared__ __align__(16) unsigned short Alds[128 * 32];
  __shared__ __align__(16) unsigned short Blds[128 * 32];
  const int z = blockIdx.z;
  const unsigned short* Bm = (z == 0) ? gp.B0 : ((z == 1) ? gp.B1 : gp.B2);
  const float* bias = (z == 0) ? gp.bias0 : ((z == 1) ? gp.bias1 : gp.bias2);
  float* out = (z == 0) ? gp.out0 : ((z == 1) ? gp.out1 : gp.out2);
  const int n0 = blockIdx.x * 128;
  const int t0 = blockIdx.y * 128;
  const int tid = threadIdx.x;
  const int wave = tid >> 6;
  const int lane = tid & 63;
  const int wr = wave >> 1, wc = wave & 1;
  const int row16 = lane & 15, kq = lane >> 4;

  f32x4 acc[4][4] = {};

  for (int k0 = 0; k0 < KDIM; k0 += 32) {
    // Stage A and B tiles: 8 KiB each = 8 segments of 1 KiB; each wave stages 2 segments per tile.
    // LDS dest is wave-uniform base + lane*16 (global_load_lds semantics, m104/m108).
#pragma unroll
    for (int s = 0; s < 2; ++s) {
      const int seg = wave * 2 + s;
      const int off = seg * 1024 + lane * 16;  // byte offset in tile
      const int row = off >> 6;                // 64 B per row (32 bf16)
      const int ke = (off & 63) >> 1;          // element offset in row
      const unsigned short* ga = A + (size_t)(t0 + row) * KDIM + (k0 + ke);
      __builtin_amdgcn_global_load_lds((u32_as1*)ga, (u32_as3*)(Alds + seg * 512), 16, 0, 0);
      const unsigned short* gb = Bm + (size_t)(n0 + row) * KDIM + (k0 + ke);
      __builtin_amdgcn_global_load_lds((u32_as1*)gb, (u32_as3*)(Blds + seg * 512), 16, 0, 0);
    }
    __syncthreads();

    const unsigned short* Ab = Alds + (wr * 64 + row16) * 32 + kq * 8;
    const unsigned short* Bb = Blds + (wc * 64 + row16) * 32 + kq * 8;
    bf16x8 af[4], bfr[4];
#pragma unroll
    for (int mf = 0; mf < 4; ++mf) af[mf] = *reinterpret_cast<const bf16x8*>(Ab + mf * 16 * 32);
#pragma unroll
    for (int nf = 0; nf < 4; ++nf) bfr[nf] = *reinterpret_cast<const bf16x8*>(Bb + nf * 16 * 32);
#pragma unroll
    for (int mf = 0; mf < 4; ++mf)
#pragma unroll
      for (int nf = 0; nf < 4; ++nf)
        acc[mf][nf] = __builtin_amdgcn_mfma_f32_16x16x32_bf16(af[mf], bfr[nf], acc[mf][nf], 0, 0, 0);
    __syncthreads();
  }

  // Epilogue: C/D layout col = lane&15, row = (lane>>4)*4 + reg (m89-verified)
#pragma unroll
  for (int mf = 0; mf < 4; ++mf) {
#pragma unroll
    for (int nf = 0; nf < 4; ++nf) {
      const int n = n0 + wc * 64 + nf * 16 + row16;
      const float bs = bias[n];
#pragma unroll
      for (int r = 0; r < 4; ++r) {
        const int t = t0 + wr * 64 + mf * 16 + kq * 4 + r;
        out[(size_t)t * NDIM + n] = acc[mf][nf][r] + bs;
      }
    }
  }
}

// ---------------- Gate elementwise: in-place a over r_pre, gx over i_pre ----------------
__device__ __forceinline__ void gate1(float rp, float ip, float xv, float dcv, float& a, float& g) {
  const float r = 1.0f / (1.0f + expf(-rp));
  a = expf(dcv * r);
  const float ii = 1.0f / (1.0f + expf(-ip));
  g = sqrtf(fmaxf(0.0f, 1.0f - a * a)) * (ii * xv);
}

__global__ void gate_ew(float* ra, float* ig, const float* __restrict__ xp, const float* __restrict__ dec) {
  const size_t i = (size_t)blockIdx.x * 256 + threadIdx.x;
  float4 r4 = reinterpret_cast<float4*>(ra)[i];
  float4 i4 = reinterpret_cast<float4*>(ig)[i];
  const float4 x4 = reinterpret_cast<const float4*>(xp)[i];
  const int d0 = (int)((i * 4) & (DHID - 1));
  const float4 dc = *reinterpret_cast<const float4*>(dec + d0);
  float4 a4, g4;
  gate1(r4.x, i4.x, x4.x, dc.x, a4.x, g4.x);
  gate1(r4.y, i4.y, x4.y, dc.y, a4.y, g4.y);
  gate1(r4.z, i4.z, x4.z, dc.z, a4.z, g4.z);
  gate1(r4.w, i4.w, x4.w, dc.w, a4.w, g4.w);
  reinterpret_cast<float4*>(ra)[i] = a4;
  reinterpret_cast<float4*>(ig)[i] = g4;
}

// ---------------- Chunked scan: h_t = a_t * h_{t-1} + b_t ----------------
__global__ void scan_pass1(const float* __restrict__ a, const float* __restrict__ b,
                           float* __restrict__ aggA, float* __restrict__ aggB) {
  const int d = blockIdx.y * 256 + threadIdx.x;
  const int c = blockIdx.x;
  const size_t base = (size_t)c * CLEN * DHID + d;
  float h = 0.0f, p = 1.0f;
#pragma unroll 4
  for (int t = 0; t < CLEN; ++t) {
    const float av = a[base + (size_t)t * DHID];
    const float bv = b[base + (size_t)t * DHID];
    h = fmaf(av, h, bv);
    p *= av;
  }
  aggA[c * DHID + d] = p;
  aggB[c * DHID + d] = h;
}

__global__ void scan_pass2(const float* __restrict__ aggA, const float* __restrict__ aggB,
                           float* __restrict__ pref) {
  const int d = blockIdx.x * 256 + threadIdx.x;
  float p = 0.0f;
  for (int c = 0; c < NCHUNK; ++c) {
    p = fmaf(aggA[c * DHID + d], p, aggB[c * DHID + d]);
    pref[c * DHID + d] = p;
  }
}

__global__ void scan_pass3(const float* __restrict__ a, const float* __restrict__ b,
                           const float* __restrict__ pref, unsigned short* __restrict__ hbf) {
  const int d = blockIdx.y * 256 + threadIdx.x;
  const int c = blockIdx.x;
  float h = (c == 0) ? 0.0f : pref[(c - 1) * DHID + d];
  const size_t base = (size_t)c * CLEN * DHID + d;
#pragma unroll 4
  for (int t = 0; t < CLEN; ++t) {
    const float av = a[base + (size_t)t * DHID];
    const float bv = b[base + (size_t)t * DHID];
    h = fmaf(av, h, bv);
    hbf[base + (size_t)t * DHID] = bf16r(h);
  }
}

extern "C" void kernel_launch(void* const* d_in, const int* in_sizes, int n_in,
                              void* d_out, int out_size, void* d_ws, size_t ws_size,
                              hipStream_t stream) {
  const float* inputs = (const float*)d_in[0];
  const float* pre_a = (const float*)d_in[1];
  const float* Wr = (const float*)d_in[2];
  const float* br = (const float*)d_in[3];
  const float* Wi = (const float*)d_in[4];
  const float* bi = (const float*)d_in[5];
  const float* Wx = (const float*)d_in[6];
  const float* bx = (const float*)d_in[7];
  const float* Wo = (const float*)d_in[8];
  const float* bo = (const float*)d_in[9];
  float* out = (float*)d_out;

  char* ws = (char*)d_ws;
  size_t off = 0;
  auto alloc = [&](size_t bytes) {
    char* p = ws + off;
    off += (bytes + 255) & ~(size_t)255;
    return p;
  };
  unsigned short* Xbf = (unsigned short*)alloc((size_t)TT * DIN * 2);
  unsigned short* Wrbf = (unsigned short*)alloc((size_t)DHID * DIN * 2);
  unsigned short* Wibf = (unsigned short*)alloc((size_t)DHID * DIN * 2);
  unsigned short* Wxbf = (unsigned short*)alloc((size_t)DHID * DIN * 2);
  unsigned short* Wobf = (unsigned short*)alloc((size_t)DOUT * DHID * 2);
  float* rpre = (float*)alloc((size_t)TT * DHID * 4);
  float* ipre = (float*)alloc((size_t)TT * DHID * 4);
  float* xpre = (float*)alloc((size_t)TT * DHID * 4);
  float* dec = (float*)alloc(DHID * 4);
  float* aggA = (float*)alloc((size_t)NCHUNK * DHID * 4);
  float* aggB = (float*)alloc((size_t)NCHUNK * DHID * 4);
  float* pref = (float*)alloc((size_t)NCHUNK * DHID * 4);
  unsigned short* hbf = (unsigned short*)xpre;  // reuse: xpre dead after gate_ew
  if (off > ws_size) return;                    // workspace too small: fail visibly

  // Casts to bf16
  cast_f32_bf16<<<TT * DIN / 4 / 256, 256, 0, stream>>>(inputs, Xbf, TT * DIN / 4);
  cast_f32_bf16<<<DHID * DIN / 4 / 256, 256, 0, stream>>>(Wr, Wrbf, DHID * DIN / 4);
  cast_f32_bf16<<<DHID * DIN / 4 / 256, 256, 0, stream>>>(Wi, Wibf, DHID * DIN / 4);
  cast_f32_bf16<<<DHID * DIN / 4 / 256, 256, 0, stream>>>(Wx, Wxbf, DHID * DIN / 4);
  cast_f32_bf16<<<DOUT * DHID / 4 / 256, 256, 0, stream>>>(Wo, Wobf, DOUT * DHID / 4);
  dec_kernel<<<DHID / 256, 256, 0, stream>>>(pre_a, dec);

  // Gate GEMMs (one dispatch, z selects Wr/Wi/Wx)
  GemmPtrs g1 = {Wrbf, Wibf, Wxbf, br, bi, bx, rpre, ipre, xpre};
  gemm_bt<DIN, DHID><<<dim3(DHID / 128, TT / 128, 3), 256, 0, stream>>>(Xbf, g1);

  // Gate nonlinearity (in-place: rpre -> a, ipre -> gx)
  gate_ew<<<TT * DHID / 4 / 256, 256, 0, stream>>>(rpre, ipre, xpre, dec);

  // Chunked scan
  scan_pass1<<<dim3(NCHUNK, DHID / 256), 256, 0, stream>>>(rpre, ipre, aggA, aggB);
  scan_pass2<<<DHID / 256, 256, 0, stream>>>(aggA, aggB, pref);
  scan_pass3<<<dim3(NCHUNK, DHID / 256), 256, 0, stream>>>(rpre, ipre, pref, hbf);

  // Output projection
  GemmPtrs g2 = {Wobf, nullptr, nullptr, bo, nullptr, nullptr, out, nullptr, nullptr};
  gemm_bt<DHID, DOUT><<<dim3(DOUT / 128, TT / 128, 1), 256, 0, stream>>>(hbf, g2);
}

// Round 2
// 254.722 us; speedup vs baseline: 1.2536x; 1.2536x over previous
//
#include <hip/hip_runtime.h>
#include <cstdint>
#include <cstddef>

#define TT 8192
#define DIN 1024
#define DHID 2048
#define DOUT 1024
#define NCHUNK 128
#define CLEN 64  // TT / NCHUNK

typedef __bf16 bf16x8 __attribute__((ext_vector_type(8)));
typedef float f32x4 __attribute__((ext_vector_type(4)));
using u32_as1 = __attribute__((address_space(1))) const unsigned int;
using u32_as3 = __attribute__((address_space(3))) unsigned int;

__device__ __forceinline__ unsigned short bf16r(float x) {
  unsigned int u = __float_as_uint(x);
  u += 0x7fffu + ((u >> 16) & 1u);
  return (unsigned short)(u >> 16);
}

__device__ __forceinline__ float bf16tof(unsigned short u) {
  return __uint_as_float(((unsigned int)u) << 16);
}

__global__ void cast_f32_bf16(const float* __restrict__ in, unsigned short* __restrict__ out, int n4) {
  int i = blockIdx.x * 256 + threadIdx.x;
  if (i >= n4) return;
  const float4 v = reinterpret_cast<const float4*>(in)[i];
  ushort4 o;
  o.x = bf16r(v.x);
  o.y = bf16r(v.y);
  o.z = bf16r(v.z);
  o.w = bf16r(v.w);
  reinterpret_cast<ushort4*>(out)[i] = o;
}

__global__ void dec_kernel(const float* __restrict__ pre_a, float* __restrict__ dec) {
  const int d = blockIdx.x * 256 + threadIdx.x;
  if (d < DHID) dec[d] = -8.0f * log1pf(expf(pre_a[d]));
}

// ---------------- Fused gate GEMM ----------------
// Computes r,i,x pre-acts for a (128 t x 64 n) tile with one shared A-tile and
// three B-tiles per K-step, then applies the gate nonlinearity in the epilogue:
//   a  = exp(dec[n] * sigmoid(rpre))           -> fp32 (scan multiplies it; keep precise)
//   gx = sqrt(1-a^2) * sigmoid(ipre) * xpre    -> bf16 (additive contribution, 0.2% ok)
// 4 waves, per-wave 64x32 per matrix: acc[3][4][2] (96 VGPRs) keeps 3 waves/SIMD.
__global__ __launch_bounds__(256) void gemm_gates(
    const unsigned short* __restrict__ X, const unsigned short* __restrict__ Wr,
    const unsigned short* __restrict__ Wi, const unsigned short* __restrict__ Wx,
    const float* __restrict__ br, const float* __restrict__ bi, const float* __restrict__ bx,
    const float* __restrict__ dec, float* __restrict__ a_out, unsigned short* __restrict__ gx_out) {
  __shared__ __align__(16) unsigned short lds[(128 + 3 * 64) * 32];  // A:8KB + 3x B:4KB = 20KB
  const int n0 = blockIdx.x * 64;
  const int t0 = blockIdx.y * 128;
  const int tid = threadIdx.x;
  const int wave = tid >> 6, lane = tid & 63;
  const int wr = wave >> 1, wc = wave & 1;
  const int row16 = lane & 15, kq = lane >> 4;

  f32x4 acc[3][4][2] = {};

  for (int k0 = 0; k0 < DIN; k0 += 32) {
    // 20 segments of 1 KiB: A = segs 0..7 (128 rows x 32), Bz = 4 segs each.
    // seg id is wave-uniform; global_load_lds dest = uniform base + lane*16 (m104/m108).
#pragma unroll
    for (int s = 0; s < 5; ++s) {
      const int seg = wave * 5 + s;
      const int lb = lane * 16;
      if (seg < 8) {
        const int off = seg * 1024 + lb;
        const int row = off >> 6, ke = (off & 63) >> 1;
        __builtin_amdgcn_global_load_lds((u32_as1*)(X + (size_t)(t0 + row) * DIN + k0 + ke),
                                         (u32_as3*)(lds + seg * 512), 16, 0, 0);
      } else {
        const int m = (seg - 8) >> 2, sub = (seg - 8) & 3;
        const unsigned short* Bm = (m == 0) ? Wr : ((m == 1) ? Wi : Wx);
        const int off = sub * 1024 + lb;
        const int row = off >> 6, ke = (off & 63) >> 1;
        __builtin_amdgcn_global_load_lds((u32_as1*)(Bm + (size_t)(n0 + row) * DIN + k0 + ke),
                                         (u32_as3*)(lds + (128 + m * 64) * 32 + sub * 512), 16, 0, 0);
      }
    }
    __syncthreads();

    const unsigned short* Ab = lds + (wr * 64 + row16) * 32 + kq * 8;
    bf16x8 af[4];
#pragma unroll
    for (int mf = 0; mf < 4; ++mf) af[mf] = *reinterpret_cast<const bf16x8*>(Ab + mf * 16 * 32);
#pragma unroll
    for (int z = 0; z < 3; ++z) {
      const unsigned short* Bb = lds + (128 + z * 64 + wc * 32 + row16) * 32 + kq * 8;
      const bf16x8 b0 = *reinterpret_cast<const bf16x8*>(Bb);
      const bf16x8 b1 = *reinterpret_cast<const bf16x8*>(Bb + 16 * 32);
#pragma unroll
      for (int mf = 0; mf < 4; ++mf) {
        acc[z][mf][0] = __builtin_amdgcn_mfma_f32_16x16x32_bf16(af[mf], b0, acc[z][mf][0], 0, 0, 0);
        acc[z][mf][1] = __builtin_amdgcn_mfma_f32_16x16x32_bf16(af[mf], b1, acc[z][mf][1], 0, 0, 0);
      }
    }
    __syncthreads();
  }

  // Epilogue: C/D layout col = lane&15, row = (lane>>4)*4 + reg (m89-verified)
#pragma unroll
  for (int nf = 0; nf < 2; ++nf) {
    const int n = n0 + wc * 32 + nf * 16 + row16;
    const float brv = br[n], biv = bi[n], bxv = bx[n], dcv = dec[n];
#pragma unroll
    for (int mf = 0; mf < 4; ++mf) {
#pragma unroll
      for (int r = 0; r < 4; ++r) {
        const int t = t0 + wr * 64 + mf * 16 + kq * 4 + r;
        const float rp = acc[0][mf][nf][r] + brv;
        const float ip = acc[1][mf][nf][r] + biv;
        const float xv = acc[2][mf][nf][r] + bxv;
        const float rs = __builtin_amdgcn_rcpf(1.0f + __expf(-rp));
        const float av = __expf(dcv * rs);
        const float is = __builtin_amdgcn_rcpf(1.0f + __expf(-ip));
        const float gv = sqrtf(fmaxf(0.0f, 1.0f - av * av)) * (is * xv);
        a_out[(size_t)t * DHID + n] = av;
        gx_out[(size_t)t * DHID + n] = bf16r(gv);
      }
    }
  }
}

// ---------------- Plain GEMM for the output projection ----------------
// out[t][n] = sum_k A[t][k] * B[n][k] + bias[n]; 128x128 tile, BK=32, 4 waves.
template <int KDIM, int NDIM>
__global__ __launch_bounds__(256) void gemm_bt(const unsigned short* __restrict__ A,
                                               const unsigned short* __restrict__ B,
                                               const float* __restrict__ bias,
                                               float* __restrict__ out) {
  __shared__ __align__(16) unsigned short Alds[128 * 32];
  __shared__ __align__(16) unsigned short Blds[128 * 32];
  const int n0 = blockIdx.x * 128;
  const int t0 = blockIdx.y * 128;
  const int tid = threadIdx.x;
  const int wave = tid >> 6, lane = tid & 63;
  const int wr = wave >> 1, wc = wave & 1;
  const int row16 = lane & 15, kq = lane >> 4;

  f32x4 acc[4][4] = {};

  for (int k0 = 0; k0 < KDIM; k0 += 32) {
#pragma unroll
    for (int s = 0; s < 2; ++s) {
      const int seg = wave * 2 + s;
      const int off = seg * 1024 + lane * 16;
      const int row = off >> 6;
      const int ke = (off & 63) >> 1;
      __builtin_amdgcn_global_load_lds((u32_as1*)(A + (size_t)(t0 + row) * KDIM + k0 + ke),
                                       (u32_as3*)(Alds + seg * 512), 16, 0, 0);
      __builtin_amdgcn_global_load_lds((u32_as1*)(B + (size_t)(n0 + row) * KDIM + k0 + ke),
                                       (u32_as3*)(Blds + seg * 512), 16, 0, 0);
    }
    __syncthreads();

    const unsigned short* Ab = Alds + (wr * 64 + row16) * 32 + kq * 8;
    const unsigned short* Bb = Blds + (wc * 64 + row16) * 32 + kq * 8;
    bf16x8 af[4], bfr[4];
#pragma unroll
    for (int mf = 0; mf < 4; ++mf) af[mf] = *reinterpret_cast<const bf16x8*>(Ab + mf * 16 * 32);
#pragma unroll
    for (int nf = 0; nf < 4; ++nf) bfr[nf] = *reinterpret_cast<const bf16x8*>(Bb + nf * 16 * 32);
#pragma unroll
    for (int mf = 0; mf < 4; ++mf)
#pragma unroll
      for (int nf = 0; nf < 4; ++nf)
        acc[mf][nf] = __builtin_amdgcn_mfma_f32_16x16x32_bf16(af[mf], bfr[nf], acc[mf][nf], 0, 0, 0);
    __syncthreads();
  }

#pragma unroll
  for (int mf = 0; mf < 4; ++mf) {
#pragma unroll
    for (int nf = 0; nf < 4; ++nf) {
      const int n = n0 + wc * 64 + nf * 16 + row16;
      const float bs = bias[n];
#pragma unroll
      for (int r = 0; r < 4; ++r) {
        const int t = t0 + wr * 64 + mf * 16 + kq * 4 + r;
        out[(size_t)t * NDIM + n] = acc[mf][nf][r] + bs;
      }
    }
  }
}

// ---------------- Chunked scan: h_t = a_t * h_{t-1} + gx_t ----------------
__global__ void scan_pass1(const float* __restrict__ a, const unsigned short* __restrict__ gx,
                           float* __restrict__ aggA, float* __restrict__ aggB) {
  const int d = blockIdx.y * 256 + threadIdx.x;
  const int c = blockIdx.x;
  const size_t base = (size_t)c * CLEN * DHID + d;
  float h = 0.0f, p = 1.0f;
#pragma unroll 4
  for (int t = 0; t < CLEN; ++t) {
    const float av = a[base + (size_t)t * DHID];
    const float bv = bf16tof(gx[base + (size_t)t * DHID]);
    h = fmaf(av, h, bv);
    p *= av;
  }
  aggA[c * DHID + d] = p;
  aggB[c * DHID + d] = h;
}

__global__ void scan_pass2(const float* __restrict__ aggA, const float* __restrict__ aggB,
                           float* __restrict__ pref) {
  const int d = blockIdx.x * 256 + threadIdx.x;
  float p = 0.0f;
  for (int c = 0; c < NCHUNK; ++c) {
    p = fmaf(aggA[c * DHID + d], p, aggB[c * DHID + d]);
    pref[c * DHID + d] = p;
  }
}

__global__ void scan_pass3(const float* __restrict__ a, const unsigned short* __restrict__ gx,
                           const float* __restrict__ pref, unsigned short* __restrict__ hbf) {
  const int d = blockIdx.y * 256 + threadIdx.x;
  const int c = blockIdx.x;
  float h = (c == 0) ? 0.0f : pref[(c - 1) * DHID + d];
  const size_t base = (size_t)c * CLEN * DHID + d;
#pragma unroll 4
  for (int t = 0; t < CLEN; ++t) {
    const float av = a[base + (size_t)t * DHID];
    const float bv = bf16tof(gx[base + (size_t)t * DHID]);
    h = fmaf(av, h, bv);
    hbf[base + (size_t)t * DHID] = bf16r(h);
  }
}

extern "C" void kernel_launch(void* const* d_in, const int* in_sizes, int n_in,
                              void* d_out, int out_size, void* d_ws, size_t ws_size,
                              hipStream_t stream) {
  const float* inputs = (const float*)d_in[0];
  const float* pre_a = (const float*)d_in[1];
  const float* Wr = (const float*)d_in[2];
  const float* br = (const float*)d_in[3];
  const float* Wi = (const float*)d_in[4];
  const float* bi = (const float*)d_in[5];
  const float* Wx = (const float*)d_in[6];
  const float* bx = (const float*)d_in[7];
  const float* Wo = (const float*)d_in[8];
  const float* bo = (const float*)d_in[9];
  float* out = (float*)d_out;

  char* ws = (char*)d_ws;
  size_t off = 0;
  auto alloc = [&](size_t bytes) {
    char* p = ws + off;
    off += (bytes + 255) & ~(size_t)255;
    return p;
  };
  unsigned short* Xbf = (unsigned short*)alloc((size_t)TT * DIN * 2);
  unsigned short* Wrbf = (unsigned short*)alloc((size_t)DHID * DIN * 2);
  unsigned short* Wibf = (unsigned short*)alloc((size_t)DHID * DIN * 2);
  unsigned short* Wxbf = (unsigned short*)alloc((size_t)DHID * DIN * 2);
  unsigned short* Wobf = (unsigned short*)alloc((size_t)DOUT * DHID * 2);
  float* a_buf = (float*)alloc((size_t)TT * DHID * 4);
  unsigned short* gx_buf = (unsigned short*)alloc((size_t)TT * DHID * 2);
  unsigned short* hbf = (unsigned short*)alloc((size_t)TT * DHID * 2);
  float* dec = (float*)alloc(DHID * 4);
  float* aggA = (float*)alloc((size_t)NCHUNK * DHID * 4);
  float* aggB = (float*)alloc((size_t)NCHUNK * DHID * 4);
  float* pref = (float*)alloc((size_t)NCHUNK * DHID * 4);
  if (off > ws_size) return;  // workspace too small: fail visibly

  // Casts to bf16
  cast_f32_bf16<<<TT * DIN / 4 / 256, 256, 0, stream>>>(inputs, Xbf, TT * DIN / 4);
  cast_f32_bf16<<<DHID * DIN / 4 / 256, 256, 0, stream>>>(Wr, Wrbf, DHID * DIN / 4);
  cast_f32_bf16<<<DHID * DIN / 4 / 256, 256, 0, stream>>>(Wi, Wibf, DHID * DIN / 4);
  cast_f32_bf16<<<DHID * DIN / 4 / 256, 256, 0, stream>>>(Wx, Wxbf, DHID * DIN / 4);
  cast_f32_bf16<<<DOUT * DHID / 4 / 256, 256, 0, stream>>>(Wo, Wobf, DOUT * DHID / 4);
  dec_kernel<<<DHID / 256, 256, 0, stream>>>(pre_a, dec);

  // Fused gate GEMM + nonlinearity -> a (fp32), gx (bf16)
  gemm_gates<<<dim3(DHID / 64, TT / 128), 256, 0, stream>>>(Xbf, Wrbf, Wibf, Wxbf, br, bi, bx, dec,
                                                            a_buf, gx_buf);

  // Chunked scan
  scan_pass1<<<dim3(NCHUNK, DHID / 256), 256, 0, stream>>>(a_buf, gx_buf, aggA, aggB);
  scan_pass2<<<DHID / 256, 256, 0, stream>>>(aggA, aggB, pref);
  scan_pass3<<<dim3(NCHUNK, DHID / 256), 256, 0, stream>>>(a_buf, gx_buf, pref, hbf);

  // Output projection
  gemm_bt<DHID, DOUT><<<dim3(DOUT / 128, TT / 128), 256, 0, stream>>>(hbf, Wobf, bo, out);
}